// Round 10
// baseline (149.267 us; speedup 1.0000x reference)
//
#include <hip/hip_runtime.h>
#include <hip/hip_bf16.h>

#define CCH   512
#define BATCH 8
#define NPOS  1024
#define MQKV  1536
#define EPS   1e-5f
#define LOG2E 1.4426950408889634f

typedef __attribute__((ext_vector_type(4))) float f32x4;
typedef __attribute__((ext_vector_type(8))) __bf16 bf16x8;
typedef __attribute__((ext_vector_type(8))) unsigned short u16x8;
typedef __attribute__((ext_vector_type(4))) unsigned short u16x4;

__device__ inline unsigned short f2bf(float f) {
  __hip_bfloat16 h = __float2bfloat16(f);
  return __builtin_bit_cast(unsigned short, h);
}
__device__ inline float bf2f(unsigned short u) {
  return __bfloat162float(__builtin_bit_cast(__hip_bfloat16, u));
}

// LDS xor-swizzle (T2): ushort index within a [row][64] tile.
__device__ inline int sw(int row, int col) { return row * 64 + (col ^ ((row & 7) << 3)); }

// 16B async global->LDS. LDS dest is wave-uniform; HW scatters lane i at dst + i*16B.
__device__ inline void gload16(const void* g, void* l) {
  __builtin_amdgcn_global_load_lds((const __attribute__((address_space(1))) void*)g,
                                   (__attribute__((address_space(3))) void*)l, 16, 0, 0);
}

// ---------------- 1. fused setup: prep_weights | cpb_table | layernorm ----------------
// blocks [0,3072): weights fp32->bf16 (q rows pre-scaled 0.125*log2e)
// blocks [3072,5057): CPB table, 2 d0 per block -> table[8][3969] (scaled log2e)
// blocks [5057,5313): channel LN -> xnT[8192][512] bf16
__global__ __launch_bounds__(256) void setup_kernel(
    const float* __restrict__ wq, const float* __restrict__ wo,
    unsigned short* __restrict__ wqb, unsigned short* __restrict__ wob,
    const float* __restrict__ w0, const float* __restrict__ b0,
    const float* __restrict__ w1, const float* __restrict__ b1,
    const float* __restrict__ w2, const float* __restrict__ b2,
    float* __restrict__ table,
    const float* __restrict__ x, const float* __restrict__ gamma,
    unsigned short* __restrict__ xnT) {
  __shared__ float sh1[2][128];
  __shared__ float sh2[2][128];
  __shared__ float red[4][32][2];
  __shared__ float gsh[512];
  __shared__ unsigned short obuf[32 * 520];
  int bid = blockIdx.x, tid = threadIdx.x;

  if (bid < 3072) {
    int i = bid * 256 + tid;
    if (i < MQKV * CCH) {
      float v = wq[i];
      if (i < 512 * CCH) v *= 0.125f * LOG2E;   // scores arrive in log2 domain
      wqb[i] = f2bf(v);
    }
    if (i < CCH * CCH) wob[i] = f2bf(wo[i]);
  } else if (bid < 5057) {
    int sub = tid >> 7, t = tid & 127;
    int d0 = (bid - 3072) * 2 + sub;
    bool ok = d0 < 3969;
    int d0c = ok ? d0 : 0;
    int dy = d0c / 63 - 31, dx = d0c % 63 - 31;
    float r0 = (dy > 0 ? 1.f : (dy < 0 ? -1.f : 0.f)) * logf(fabsf((float)dy) + 1.f);
    float r1 = (dx > 0 ? 1.f : (dx < 0 ? -1.f : 0.f)) * logf(fabsf((float)dx) + 1.f);
    float h0 = r0 * w0[t * 2 + 0] + r1 * w0[t * 2 + 1] + b0[t];
    sh1[sub][t] = (h0 >= 0.f) ? h0 : 0.1f * h0;
    __syncthreads();
    float a = b1[t];
    #pragma unroll 8
    for (int c = 0; c < 128; ++c) a += sh1[sub][c] * w1[t * 128 + c];
    sh2[sub][t] = (a >= 0.f) ? a : 0.1f * a;
    __syncthreads();
    if (t < 8 && ok) {
      float o = b2[t];
      #pragma unroll 8
      for (int c = 0; c < 128; ++c) o += sh2[sub][c] * w2[t * 128 + c];
      table[t * 3969 + d0] = o * LOG2E;
    }
  } else {
    int blk = bid - 5057;                        // 256 = 8 b * 32 pblocks
    int b = blk >> 5, p0 = (blk & 31) * 32;
    int pl = tid & 31, wv = tid >> 6, cg = tid >> 5;
    gsh[tid] = gamma[tid];
    gsh[tid + 256] = gamma[tid + 256];
    const float* xp = x + (size_t)b * CCH * NPOS + p0 + pl;
    float vals[64];
    float s1 = 0.f, s2 = 0.f;
    #pragma unroll
    for (int j = 0; j < 64; ++j) {
      float v = xp[(size_t)(cg + 8 * j) * NPOS];
      vals[j] = v; s1 += v; s2 += v * v;
    }
    s1 += __shfl_xor(s1, 32, 64); s2 += __shfl_xor(s2, 32, 64);
    if ((tid & 63) < 32) { red[wv][pl][0] = s1; red[wv][pl][1] = s2; }
    __syncthreads();
    float t1 = 0.f, t2 = 0.f;
    #pragma unroll
    for (int w2i = 0; w2i < 4; ++w2i) { t1 += red[w2i][pl][0]; t2 += red[w2i][pl][1]; }
    float mean = t1 * (1.f / 512.f);
    float var = t2 * (1.f / 512.f) - mean * mean;
    float rstd = rsqrtf(var + EPS);
    #pragma unroll
    for (int j = 0; j < 64; ++j) {
      int c = cg + 8 * j;
      obuf[pl * 520 + c] = f2bf((vals[j] - mean) * rstd * gsh[c]);
    }
    __syncthreads();
    unsigned short* orow = xnT + ((size_t)b * NPOS + p0) * 512;
    #pragma unroll
    for (int i = 0; i < 8; ++i) {
      int c2 = tid + i * 256;
      int pp = c2 >> 6, ch = c2 & 63;
      *(u16x8*)&orow[(size_t)pp * 512 + ch * 8] = *(const u16x8*)&obuf[pp * 520 + ch * 8];
    }
  }
}

// ---------------- 2. fused qkv-GEMM + bias_expand ----------------
// blocks [0,768): 128x128 GEMM qkv = wqb * xnT^T with LDS-bounced scatter epilogue.
// blocks [768,33536): bias expand table -> biasP (fragment-permuted), backfills CUs.
__global__ __launch_bounds__(256) void gemm0_bias(
    const unsigned short* __restrict__ Ag, const unsigned short* __restrict__ Bg,
    unsigned short* __restrict__ qT, unsigned short* __restrict__ kT,
    unsigned short* __restrict__ vB,
    const float* __restrict__ table, unsigned short* __restrict__ biasP) {
  __shared__ unsigned short smem[2 * 128 * 64];   // As | Bs; reused as 128x128 C-tile
  int bid = blockIdx.x, tid = threadIdx.x;

  if (bid >= 768) {
    int idx = (bid - 768) * 256 + tid;            // 8M total, idx == output address
    int h = idx >> 20;
    int i = (idx >> 10) & 1023;
    int blk = (idx >> 6) & 15;
    int q = idx & 63;
    int l16q = q >> 2, jt = q & 3;
    int j = blk * 64 + jt * 16 + l16q;
    int dy = (i >> 5) - (j >> 5) + 31;
    int dx = (i & 31) - (j & 31) + 31;
    biasP[idx] = f2bf(table[h * 3969 + dy * 63 + dx]);
    return;
  }

  unsigned short* As = smem;
  unsigned short* Bs = smem + 128 * 64;
  int by = bid >> 6;
  int m0 = by * 128, nn0 = (bid & 63) * 128;
  int wave = tid >> 6, lane = tid & 63;
  int wm = wave >> 1, wn = wave & 1;
  int l16 = lane & 15, lh = lane >> 4;
  int rsub = lane >> 3, csub = lane & 7;
  int scsw = (csub ^ rsub) * 8;                   // pre-swizzled source col (ushorts)
  f32x4 acc[4][4];
  #pragma unroll
  for (int it = 0; it < 4; ++it)
    #pragma unroll
    for (int jt = 0; jt < 4; ++jt) acc[it][jt] = (f32x4){0.f, 0.f, 0.f, 0.f};

  for (int k0 = 0; k0 < 512; k0 += 64) {
    #pragma unroll
    for (int i = 0; i < 4; ++i) {
      int grp = wave * 4 + i;                     // 16 groups of 8 rows
      int row = grp * 8 + rsub;
      gload16(&Ag[(size_t)(m0 + row) * 512 + k0 + scsw], &As[grp * 512]);
      gload16(&Bg[(size_t)(nn0 + row) * 512 + k0 + scsw], &Bs[grp * 512]);
    }
    __syncthreads();
    #pragma unroll
    for (int ks = 0; ks < 2; ++ks) {
      int koff = ks * 32 + lh * 8;
      bf16x8 a[4], b[4];
      #pragma unroll
      for (int it = 0; it < 4; ++it) a[it] = *(const bf16x8*)&As[sw(wm * 64 + it * 16 + l16, koff)];
      #pragma unroll
      for (int jt = 0; jt < 4; ++jt) b[jt] = *(const bf16x8*)&Bs[sw(wn * 64 + jt * 16 + l16, koff)];
      #pragma unroll
      for (int it = 0; it < 4; ++it)
        #pragma unroll
        for (int jt = 0; jt < 4; ++jt)
          acc[it][jt] = __builtin_amdgcn_mfma_f32_16x16x32_bf16(a[it], b[jt], acc[it][jt], 0, 0, 0);
    }
    __syncthreads();
  }

  // ---- LDS-bounced coalesced epilogue ----
  int sel = by >> 2;                 // 0:q 1:k 2:v
  int hh0 = (by & 3) * 2;
  int bb = nn0 >> 10, p0 = nn0 & 1023;
  unsigned short* Cs = smem;         // 128x128 ushort = 32 KB
  if (sel < 2) {
    #pragma unroll
    for (int it = 0; it < 4; ++it)
      #pragma unroll
      for (int jt = 0; jt < 4; ++jt) {
        int nnl = wn * 64 + jt * 16 + l16;
        int mb = wm * 64 + it * 16 + lh * 4;
        #pragma unroll
        for (int r = 0; r < 4; ++r)
          Cs[nnl * 128 + ((mb + r) ^ ((nnl & 7) << 4))] = f2bf(acc[it][jt][r]);
      }
    __syncthreads();
    unsigned short* dst = (sel == 0) ? qT : kT;
    #pragma unroll
    for (int i = 0; i < 8; ++i) {
      int c = tid + i * 256;
      int hl = c >> 10, p = (c >> 3) & 127, ch = c & 7;
      int mb = hl * 64 + ch * 8;
      u16x8 val = *(u16x8*)&Cs[p * 128 + (mb ^ ((p & 7) << 4))];
      int bh = bb * 8 + hh0 + hl;
      *(u16x8*)&dst[((size_t)bh * 1024 + p0 + p) * 64 + ch * 8] = val;
    }
  } else {
    #pragma unroll
    for (int it = 0; it < 4; ++it)
      #pragma unroll
      for (int jt = 0; jt < 4; ++jt) {
        int nnl = wn * 64 + jt * 16 + l16;
        int mb = wm * 64 + it * 16 + lh * 4;
        #pragma unroll
        for (int r = 0; r < 4; ++r)
          Cs[(mb + r) * 128 + (nnl ^ (((mb + r) & 7) << 4))] = f2bf(acc[it][jt][r]);
      }
    __syncthreads();
    #pragma unroll
    for (int i = 0; i < 8; ++i) {
      int c = tid + i * 256;
      int mloc = c >> 4, ch = c & 15;
      u16x8 val = *(u16x8*)&Cs[mloc * 128 + ((ch * 8) ^ ((mloc & 7) << 4))];
      int d = mloc & 63, hl = mloc >> 6;
      int bh = bb * 8 + hh0 + hl;
      *(u16x8*)&vB[((size_t)bh * 64 + d) * 1024 + p0 + ch * 8] = val;
    }
  }
}

// ---------------- 3. GEMM out-proj + residual (MODE 1 of old gemm_bt) ----------------
__global__ __launch_bounds__(256) void gemm_out(const unsigned short* __restrict__ Ag,
                                                const unsigned short* __restrict__ Bg,
                                                const float* __restrict__ xres,
                                                float* __restrict__ yout) {
  __shared__ unsigned short smem[2 * 128 * 64];
  unsigned short* As = smem;
  unsigned short* Bs = smem + 128 * 64;
  int tid = threadIdx.x;
  int m0 = blockIdx.y * 128, nn0 = blockIdx.x * 128;
  int wave = tid >> 6, lane = tid & 63;
  int wm = wave >> 1, wn = wave & 1;
  int l16 = lane & 15, lh = lane >> 4;
  int rsub = lane >> 3, csub = lane & 7;
  int scsw = (csub ^ rsub) * 8;
  f32x4 acc[4][4];
  #pragma unroll
  for (int it = 0; it < 4; ++it)
    #pragma unroll
    for (int jt = 0; jt < 4; ++jt) acc[it][jt] = (f32x4){0.f, 0.f, 0.f, 0.f};

  for (int k0 = 0; k0 < 512; k0 += 64) {
    #pragma unroll
    for (int i = 0; i < 4; ++i) {
      int grp = wave * 4 + i;
      int row = grp * 8 + rsub;
      gload16(&Ag[(size_t)(m0 + row) * 512 + k0 + scsw], &As[grp * 512]);
      gload16(&Bg[(size_t)(nn0 + row) * 512 + k0 + scsw], &Bs[grp * 512]);
    }
    __syncthreads();
    #pragma unroll
    for (int ks = 0; ks < 2; ++ks) {
      int koff = ks * 32 + lh * 8;
      bf16x8 a[4], b[4];
      #pragma unroll
      for (int it = 0; it < 4; ++it) a[it] = *(const bf16x8*)&As[sw(wm * 64 + it * 16 + l16, koff)];
      #pragma unroll
      for (int jt = 0; jt < 4; ++jt) b[jt] = *(const bf16x8*)&Bs[sw(wn * 64 + jt * 16 + l16, koff)];
      #pragma unroll
      for (int it = 0; it < 4; ++it)
        #pragma unroll
        for (int jt = 0; jt < 4; ++jt)
          acc[it][jt] = __builtin_amdgcn_mfma_f32_16x16x32_bf16(a[it], b[jt], acc[it][jt], 0, 0, 0);
    }
    __syncthreads();
  }

  #pragma unroll
  for (int it = 0; it < 4; ++it) {
    int mbase = m0 + wm * 64 + it * 16 + lh * 4;
    #pragma unroll
    for (int jt = 0; jt < 4; ++jt) {
      int nn = nn0 + wn * 64 + jt * 16 + l16;
      int bb = nn >> 10, p = nn & 1023;
      #pragma unroll
      for (int r = 0; r < 4; ++r) {
        size_t addr = ((size_t)bb * 512 + mbase + r) * 1024 + p;
        yout[addr] = acc[it][jt][r] + xres[addr];
      }
    }
  }
}

// ---------------- 4. flash attention: 8 waves / 128 q-rows, bh-fastest grid ----------------
// K/V staged once per 128 rows (half the traffic of r9); XCD = bh%8 -> 2MB L2-resident K/V
// per XCD. gload_lds double-buffered, 1 barrier/tile. No-max softmax (elementwise exp2);
// denominator via ones-column PV accumulator.
__global__ __launch_bounds__(512) void attn_kernel(const unsigned short* __restrict__ qT,
                                                   const unsigned short* __restrict__ kT,
                                                   const unsigned short* __restrict__ vB,
                                                   const unsigned short* __restrict__ biasP,
                                                   unsigned short* __restrict__ attnout) {
  __shared__ unsigned short Kbuf[2][64 * 64];
  __shared__ unsigned short Vbuf[2][64 * 64];
  __shared__ unsigned short Ps[8][16 * 64];
  int tid = threadIdx.x;
  int bh = blockIdx.x;               // bh-fastest: XCD = bh%8
  int i0 = blockIdx.y * 128;
  int hh = bh & 7, bb = bh >> 3;
  int w = tid >> 6, lane = tid & 63, l16 = lane & 15, lh = lane >> 4;
  int rsub = lane >> 3, csub = lane & 7;
  int scsw = (csub ^ rsub) * 8;      // pre-swizzled source col (both-sides rule)

  const unsigned short* kbase = kT + (size_t)bh * NPOS * 64;
  const unsigned short* vbase = vB + (size_t)bh * 64 * NPOS;
  const unsigned short* bptr  = biasP + ((size_t)hh * 1024 + i0 + w * 16) * 1024 + l16 * 4;

  // Q fragments in registers (one q-row per lane)
  int qrow = i0 + w * 16 + l16;
  const unsigned short* qb = qT + ((size_t)bh * NPOS + qrow) * 64 + lh * 8;
  bf16x8 qreg[2];
  qreg[0] = *(const bf16x8*)&qb[0];
  qreg[1] = *(const bf16x8*)&qb[32];

  f32x4 o[5];                        // 0..3 output d-fragments, 4 = softmax denominator
  #pragma unroll
  for (int dt = 0; dt < 5; ++dt) o[dt] = (f32x4){0.f, 0.f, 0.f, 0.f};

  bf16x8 ones;
  {
    u16x8 tmp = {0x3F80, 0x3F80, 0x3F80, 0x3F80, 0x3F80, 0x3F80, 0x3F80, 0x3F80};
    ones = __builtin_bit_cast(bf16x8, tmp);
  }

  // stage tile jj: each of 8 waves stages 1 K-group + 1 V-group (1KB each)
  #define STAGE(Kd, Vd, jj) do {                                                        \
    gload16(&kbase[(size_t)((jj) + w * 8 + rsub) * 64 + scsw], &(Kd)[w * 512]);         \
    gload16(&vbase[(size_t)(w * 8 + rsub) * 1024 + (jj) + scsw], &(Vd)[w * 512]);       \
  } while (0)

  STAGE(Kbuf[0], Vbuf[0], 0);
  __syncthreads();                   // drains prologue staging

  #pragma unroll 1
  for (int t = 0; t < 16; ++t) {
    int j0 = t * 64;
    // issue next tile's staging first: in flight during this tile's compute
    if (t < 15) STAGE(Kbuf[(t + 1) & 1], Vbuf[(t + 1) & 1], j0 + 64);

    const unsigned short* Ks = Kbuf[t & 1];
    const unsigned short* Vs = Vbuf[t & 1];

    // bias preload (overlaps QK^T)
    u16x4 bv4[4];
    #pragma unroll
    for (int r = 0; r < 4; ++r) bv4[r] = *(const u16x4*)&bptr[(lh * 4 + r) * 1024 + j0];

    // ---- QK^T ----
    f32x4 s[4];
    #pragma unroll
    for (int jt = 0; jt < 4; ++jt) s[jt] = (f32x4){0.f, 0.f, 0.f, 0.f};
    #pragma unroll
    for (int ks = 0; ks < 2; ++ks) {
      int koff = ks * 32 + lh * 8;
      #pragma unroll
      for (int jt = 0; jt < 4; ++jt) {
        bf16x8 bk = *(const bf16x8*)&Ks[sw(jt * 16 + l16, koff)];
        s[jt] = __builtin_amdgcn_mfma_f32_16x16x32_bf16(qreg[ks], bk, s[jt], 0, 0, 0);
      }
    }

    // ---- elementwise softmax numerator: P = exp2(s + bias); no max, no cross-lane ----
    #pragma unroll
    for (int r = 0; r < 4; ++r) {
      int rloc = lh * 4 + r;
      #pragma unroll
      for (int jt = 0; jt < 4; ++jt) {
        float pv = __builtin_amdgcn_exp2f(s[jt][r] + bf2f(bv4[r][jt]));
        Ps[w][sw(rloc, jt * 16 + l16)] = f2bf(pv);
      }
    }

    // ---- PV (Ps wave-private: no barrier). o[4] accumulates the denominator ----
    #pragma unroll
    for (int js = 0; js < 2; ++js) {
      int koff = js * 32 + lh * 8;
      bf16x8 pa = *(const bf16x8*)&Ps[w][sw(l16, koff)];
      #pragma unroll
      for (int dt = 0; dt < 4; ++dt) {
        bf16x8 vb = *(const bf16x8*)&Vs[sw(dt * 16 + l16, koff)];
        o[dt] = __builtin_amdgcn_mfma_f32_16x16x32_bf16(pa, vb, o[dt], 0, 0, 0);
      }
      o[4] = __builtin_amdgcn_mfma_f32_16x16x32_bf16(pa, ones, o[4], 0, 0, 0);
    }

    // single barrier per tile: drains next tile's staging + protects buffer reuse
    __syncthreads();
  }

  #pragma unroll
  for (int r = 0; r < 4; ++r) {
    float inv = 1.f / o[4][r];
    int gi = i0 + w * 16 + lh * 4 + r;
    #pragma unroll
    for (int dt = 0; dt < 4; ++dt)
      attnout[((size_t)bb * 1024 + gi) * 512 + hh * 64 + dt * 16 + l16] = f2bf(o[dt][r] * inv);
  }
}

extern "C" void kernel_launch(void* const* d_in, const int* in_sizes, int n_in,
                              void* d_out, int out_size, void* d_ws, size_t ws_size,
                              hipStream_t stream) {
  const float* x     = (const float*)d_in[0];
  const float* gamma = (const float*)d_in[1];
  const float* w_qkv = (const float*)d_in[2];
  const float* w_out = (const float*)d_in[3];
  const float* cw0   = (const float*)d_in[4];
  const float* cb0   = (const float*)d_in[5];
  const float* cw1   = (const float*)d_in[6];
  const float* cb1   = (const float*)d_in[7];
  const float* cw2   = (const float*)d_in[8];
  const float* cb2   = (const float*)d_in[9];
  float* out = (float*)d_out;

  char* ws = (char*)d_ws;
  unsigned short* xnT   = (unsigned short*)(ws + 0);          // 8 MB
  unsigned short* wqb   = (unsigned short*)(ws + 8388608);    // 1.5 MB
  unsigned short* wob   = (unsigned short*)(ws + 9961472);    // 0.5 MB
  unsigned short* qT    = (unsigned short*)(ws + 10485760);   // 8 MB
  unsigned short* kT    = (unsigned short*)(ws + 18874368);   // 8 MB
  unsigned short* vB    = (unsigned short*)(ws + 27262976);   // 8 MB
  float*          table = (float*)(ws + 35651584);            // 128 KB
  unsigned short* biasP = (unsigned short*)(ws + 35782656);   // 16 MB
  unsigned short* aout  = (unsigned short*)(ws + 52559872);   // 8 MB

  setup_kernel<<<5313, 256, 0, stream>>>(w_qkv, w_out, wqb, wob,
                                         cw0, cb0, cw1, cb1, cw2, cb2, table,
                                         x, gamma, xnT);
  gemm0_bias<<<33536, 256, 0, stream>>>(wqb, xnT, qT, kT, vB, table, biasP);
  attn_kernel<<<dim3(64, 8), 512, 0, stream>>>(qT, kT, vB, biasP, aout);
  gemm_out<<<dim3(64, 4), 256, 0, stream>>>(wob, aout, x, out);
}

// Round 11
// 128.587 us; speedup vs baseline: 1.1608x; 1.1608x over previous
//
#include <hip/hip_runtime.h>
#include <hip/hip_bf16.h>

#define CCH   512
#define BATCH 8
#define NPOS  1024
#define MQKV  1536
#define EPS   1e-5f
#define LOG2E 1.4426950408889634f

typedef __attribute__((ext_vector_type(4))) float f32x4;
typedef __attribute__((ext_vector_type(8))) __bf16 bf16x8;
typedef __attribute__((ext_vector_type(8))) unsigned short u16x8;
typedef __attribute__((ext_vector_type(4))) unsigned short u16x4;

__device__ inline unsigned short f2bf(float f) {
  __hip_bfloat16 h = __float2bfloat16(f);
  return __builtin_bit_cast(unsigned short, h);
}
__device__ inline float bf2f(unsigned short u) {
  return __bfloat162float(__builtin_bit_cast(__hip_bfloat16, u));
}

// LDS xor-swizzle (T2): ushort index within a [row][64] tile.
__device__ inline int sw(int row, int col) { return row * 64 + (col ^ ((row & 7) << 3)); }

// 16B async global->LDS. LDS dest is wave-uniform; HW scatters lane i at dst + i*16B.
__device__ inline void gload16(const void* g, void* l) {
  __builtin_amdgcn_global_load_lds((const __attribute__((address_space(1))) void*)g,
                                   (__attribute__((address_space(3))) void*)l, 16, 0, 0);
}

// ---------------- 1. fused setup: prep_weights | cpb_table | layernorm ----------------
__global__ __launch_bounds__(256) void setup_kernel(
    const float* __restrict__ wq, const float* __restrict__ wo,
    unsigned short* __restrict__ wqb, unsigned short* __restrict__ wob,
    const float* __restrict__ w0, const float* __restrict__ b0,
    const float* __restrict__ w1, const float* __restrict__ b1,
    const float* __restrict__ w2, const float* __restrict__ b2,
    float* __restrict__ table,
    const float* __restrict__ x, const float* __restrict__ gamma,
    unsigned short* __restrict__ xnT) {
  __shared__ float sh1[2][128];
  __shared__ float sh2[2][128];
  __shared__ float red[4][32][2];
  __shared__ float gsh[512];
  __shared__ unsigned short obuf[32 * 520];
  int bid = blockIdx.x, tid = threadIdx.x;

  if (bid < 3072) {
    int i = bid * 256 + tid;
    if (i < MQKV * CCH) {
      float v = wq[i];
      if (i < 512 * CCH) v *= 0.125f * LOG2E;   // scores arrive in log2 domain
      wqb[i] = f2bf(v);
    }
    if (i < CCH * CCH) wob[i] = f2bf(wo[i]);
  } else if (bid < 5057) {
    int sub = tid >> 7, t = tid & 127;
    int d0 = (bid - 3072) * 2 + sub;
    bool ok = d0 < 3969;
    int d0c = ok ? d0 : 0;
    int dy = d0c / 63 - 31, dx = d0c % 63 - 31;
    float r0 = (dy > 0 ? 1.f : (dy < 0 ? -1.f : 0.f)) * logf(fabsf((float)dy) + 1.f);
    float r1 = (dx > 0 ? 1.f : (dx < 0 ? -1.f : 0.f)) * logf(fabsf((float)dx) + 1.f);
    float h0 = r0 * w0[t * 2 + 0] + r1 * w0[t * 2 + 1] + b0[t];
    sh1[sub][t] = (h0 >= 0.f) ? h0 : 0.1f * h0;
    __syncthreads();
    float a = b1[t];
    #pragma unroll 8
    for (int c = 0; c < 128; ++c) a += sh1[sub][c] * w1[t * 128 + c];
    sh2[sub][t] = (a >= 0.f) ? a : 0.1f * a;
    __syncthreads();
    if (t < 8 && ok) {
      float o = b2[t];
      #pragma unroll 8
      for (int c = 0; c < 128; ++c) o += sh2[sub][c] * w2[t * 128 + c];
      table[t * 3969 + d0] = o * LOG2E;
    }
  } else {
    int blk = bid - 5057;                        // 256 = 8 b * 32 pblocks
    int b = blk >> 5, p0 = (blk & 31) * 32;
    int pl = tid & 31, wv = tid >> 6, cg = tid >> 5;
    gsh[tid] = gamma[tid];
    gsh[tid + 256] = gamma[tid + 256];
    const float* xp = x + (size_t)b * CCH * NPOS + p0 + pl;
    float vals[64];
    float s1 = 0.f, s2 = 0.f;
    #pragma unroll
    for (int j = 0; j < 64; ++j) {
      float v = xp[(size_t)(cg + 8 * j) * NPOS];
      vals[j] = v; s1 += v; s2 += v * v;
    }
    s1 += __shfl_xor(s1, 32, 64); s2 += __shfl_xor(s2, 32, 64);
    if ((tid & 63) < 32) { red[wv][pl][0] = s1; red[wv][pl][1] = s2; }
    __syncthreads();
    float t1 = 0.f, t2 = 0.f;
    #pragma unroll
    for (int w2i = 0; w2i < 4; ++w2i) { t1 += red[w2i][pl][0]; t2 += red[w2i][pl][1]; }
    float mean = t1 * (1.f / 512.f);
    float var = t2 * (1.f / 512.f) - mean * mean;
    float rstd = rsqrtf(var + EPS);
    #pragma unroll
    for (int j = 0; j < 64; ++j) {
      int c = cg + 8 * j;
      obuf[pl * 520 + c] = f2bf((vals[j] - mean) * rstd * gsh[c]);
    }
    __syncthreads();
    unsigned short* orow = xnT + ((size_t)b * NPOS + p0) * 512;
    #pragma unroll
    for (int i = 0; i < 8; ++i) {
      int c2 = tid + i * 256;
      int pp = c2 >> 6, ch = c2 & 63;
      *(u16x8*)&orow[(size_t)pp * 512 + ch * 8] = *(const u16x8*)&obuf[pp * 520 + ch * 8];
    }
  }
}

// ---------------- 2. expand bias, fragment-permuted: [h][i][jtile(16)][l16*4+jt] ----------------
__global__ void bias_expand(const float* __restrict__ table, unsigned short* __restrict__ biasP) {
  int idx = blockIdx.x * 256 + threadIdx.x;   // 8*1024*1024 total, idx == output address
  int h = idx >> 20;
  int i = (idx >> 10) & 1023;
  int blk = (idx >> 6) & 15;
  int q = idx & 63;
  int l16 = q >> 2, jt = q & 3;
  int j = blk * 64 + jt * 16 + l16;
  int dy = (i >> 5) - (j >> 5) + 31;
  int dx = (i & 31) - (j & 31) + 31;
  biasP[idx] = f2bf(table[h * 3969 + dy * 63 + dx]);
}

// ---------------- 3. qkv GEMM: qkv = wqb * xnT^T, LDS-bounced scatter epilogue ----------------
__global__ __launch_bounds__(256) void gemm_qkv(const unsigned short* __restrict__ Ag,
                                                const unsigned short* __restrict__ Bg,
                                                unsigned short* __restrict__ qT,
                                                unsigned short* __restrict__ kT,
                                                unsigned short* __restrict__ vB) {
  __shared__ unsigned short smem[2 * 128 * 64];   // As | Bs; reused as 128x128 C-tile
  unsigned short* As = smem;
  unsigned short* Bs = smem + 128 * 64;
  int tid = threadIdx.x;
  int by = blockIdx.y;
  int m0 = by * 128, nn0 = blockIdx.x * 128;
  int wave = tid >> 6, lane = tid & 63;
  int wm = wave >> 1, wn = wave & 1;
  int l16 = lane & 15, lh = lane >> 4;
  int rsub = lane >> 3, csub = lane & 7;
  int scsw = (csub ^ rsub) * 8;                   // pre-swizzled source col (ushorts)
  f32x4 acc[4][4];
  #pragma unroll
  for (int it = 0; it < 4; ++it)
    #pragma unroll
    for (int jt = 0; jt < 4; ++jt) acc[it][jt] = (f32x4){0.f, 0.f, 0.f, 0.f};

  for (int k0 = 0; k0 < 512; k0 += 64) {
    #pragma unroll
    for (int i = 0; i < 4; ++i) {
      int grp = wave * 4 + i;                     // 16 groups of 8 rows
      int row = grp * 8 + rsub;
      gload16(&Ag[(size_t)(m0 + row) * 512 + k0 + scsw], &As[grp * 512]);
      gload16(&Bg[(size_t)(nn0 + row) * 512 + k0 + scsw], &Bs[grp * 512]);
    }
    __syncthreads();
    #pragma unroll
    for (int ks = 0; ks < 2; ++ks) {
      int koff = ks * 32 + lh * 8;
      bf16x8 a[4], b[4];
      #pragma unroll
      for (int it = 0; it < 4; ++it) a[it] = *(const bf16x8*)&As[sw(wm * 64 + it * 16 + l16, koff)];
      #pragma unroll
      for (int jt = 0; jt < 4; ++jt) b[jt] = *(const bf16x8*)&Bs[sw(wn * 64 + jt * 16 + l16, koff)];
      #pragma unroll
      for (int it = 0; it < 4; ++it)
        #pragma unroll
        for (int jt = 0; jt < 4; ++jt)
          acc[it][jt] = __builtin_amdgcn_mfma_f32_16x16x32_bf16(a[it], b[jt], acc[it][jt], 0, 0, 0);
    }
    __syncthreads();
  }

  // ---- LDS-bounced coalesced epilogue ----
  int sel = by >> 2;                 // 0:q 1:k 2:v
  int hh0 = (by & 3) * 2;
  int bb = nn0 >> 10, p0 = nn0 & 1023;
  unsigned short* Cs = smem;         // 128x128 ushort = 32 KB
  if (sel < 2) {
    #pragma unroll
    for (int it = 0; it < 4; ++it)
      #pragma unroll
      for (int jt = 0; jt < 4; ++jt) {
        int nnl = wn * 64 + jt * 16 + l16;
        int mb = wm * 64 + it * 16 + lh * 4;
        #pragma unroll
        for (int r = 0; r < 4; ++r)
          Cs[nnl * 128 + ((mb + r) ^ ((nnl & 7) << 4))] = f2bf(acc[it][jt][r]);
      }
    __syncthreads();
    unsigned short* dst = (sel == 0) ? qT : kT;
    #pragma unroll
    for (int i = 0; i < 8; ++i) {
      int c = tid + i * 256;
      int hl = c >> 10, p = (c >> 3) & 127, ch = c & 7;
      int mb = hl * 64 + ch * 8;
      u16x8 val = *(u16x8*)&Cs[p * 128 + (mb ^ ((p & 7) << 4))];
      int bh = bb * 8 + hh0 + hl;
      *(u16x8*)&dst[((size_t)bh * 1024 + p0 + p) * 64 + ch * 8] = val;
    }
  } else {
    #pragma unroll
    for (int it = 0; it < 4; ++it)
      #pragma unroll
      for (int jt = 0; jt < 4; ++jt) {
        int nnl = wn * 64 + jt * 16 + l16;
        int mb = wm * 64 + it * 16 + lh * 4;
        #pragma unroll
        for (int r = 0; r < 4; ++r)
          Cs[(mb + r) * 128 + (nnl ^ (((mb + r) & 7) << 4))] = f2bf(acc[it][jt][r]);
      }
    __syncthreads();
    #pragma unroll
    for (int i = 0; i < 8; ++i) {
      int c = tid + i * 256;
      int mloc = c >> 4, ch = c & 15;
      u16x8 val = *(u16x8*)&Cs[mloc * 128 + ((ch * 8) ^ ((mloc & 7) << 4))];
      int d = mloc & 63, hl = mloc >> 6;
      int bh = bb * 8 + hh0 + hl;
      *(u16x8*)&vB[((size_t)bh * 64 + d) * 1024 + p0 + ch * 8] = val;
    }
  }
}

// ---------------- 4. out GEMM: 64x128 tiles -> 512 blocks (2 blocks/CU) ----------------
__global__ __launch_bounds__(256) void gemm_out(const unsigned short* __restrict__ Ag,
                                                const unsigned short* __restrict__ Bg,
                                                const float* __restrict__ xres,
                                                float* __restrict__ yout) {
  __shared__ unsigned short As[64 * 64];    // 8 KB
  __shared__ unsigned short Bs[128 * 64];   // 16 KB
  int tid = threadIdx.x;
  int m0 = blockIdx.y * 64, nn0 = blockIdx.x * 128;
  int wave = tid >> 6, lane = tid & 63;
  int wm = wave >> 1, wn = wave & 1;        // 2x2 waves, each 32m x 64n
  int l16 = lane & 15, lh = lane >> 4;
  int rsub = lane >> 3, csub = lane & 7;
  int scsw = (csub ^ rsub) * 8;
  f32x4 acc[2][4];
  #pragma unroll
  for (int it = 0; it < 2; ++it)
    #pragma unroll
    for (int jt = 0; jt < 4; ++jt) acc[it][jt] = (f32x4){0.f, 0.f, 0.f, 0.f};

  for (int k0 = 0; k0 < 512; k0 += 64) {
    #pragma unroll
    for (int i = 0; i < 2; ++i) {           // A: 8 groups of 8 rows, 2 per wave
      int grp = wave * 2 + i;
      gload16(&Ag[(size_t)(m0 + grp * 8 + rsub) * 512 + k0 + scsw], &As[grp * 512]);
    }
    #pragma unroll
    for (int i = 0; i < 4; ++i) {           // B: 16 groups, 4 per wave
      int grp = wave * 4 + i;
      gload16(&Bg[(size_t)(nn0 + grp * 8 + rsub) * 512 + k0 + scsw], &Bs[grp * 512]);
    }
    __syncthreads();
    #pragma unroll
    for (int ks = 0; ks < 2; ++ks) {
      int koff = ks * 32 + lh * 8;
      bf16x8 a[2], b[4];
      #pragma unroll
      for (int it = 0; it < 2; ++it) a[it] = *(const bf16x8*)&As[sw(wm * 32 + it * 16 + l16, koff)];
      #pragma unroll
      for (int jt = 0; jt < 4; ++jt) b[jt] = *(const bf16x8*)&Bs[sw(wn * 64 + jt * 16 + l16, koff)];
      #pragma unroll
      for (int it = 0; it < 2; ++it)
        #pragma unroll
        for (int jt = 0; jt < 4; ++jt)
          acc[it][jt] = __builtin_amdgcn_mfma_f32_16x16x32_bf16(a[it], b[jt], acc[it][jt], 0, 0, 0);
    }
    __syncthreads();
  }

  #pragma unroll
  for (int it = 0; it < 2; ++it) {
    int mbase = m0 + wm * 32 + it * 16 + lh * 4;
    #pragma unroll
    for (int jt = 0; jt < 4; ++jt) {
      int nn = nn0 + wn * 64 + jt * 16 + l16;
      int bb = nn >> 10, p = nn & 1023;
      #pragma unroll
      for (int r = 0; r < 4; ++r) {
        size_t addr = ((size_t)bb * 512 + mbase + r) * 1024 + p;
        yout[addr] = acc[it][jt][r] + xres[addr];
      }
    }
  }
}

// ---------------- 5. flash attention: 8 waves / 128 q-rows, bh-fastest grid ----------------
__global__ __launch_bounds__(512) void attn_kernel(const unsigned short* __restrict__ qT,
                                                   const unsigned short* __restrict__ kT,
                                                   const unsigned short* __restrict__ vB,
                                                   const unsigned short* __restrict__ biasP,
                                                   unsigned short* __restrict__ attnout) {
  __shared__ unsigned short Kbuf[2][64 * 64];
  __shared__ unsigned short Vbuf[2][64 * 64];
  __shared__ unsigned short Ps[8][16 * 64];
  int tid = threadIdx.x;
  int bh = blockIdx.x;               // bh-fastest: XCD = bh%8
  int i0 = blockIdx.y * 128;
  int hh = bh & 7, bb = bh >> 3;
  int w = tid >> 6, lane = tid & 63, l16 = lane & 15, lh = lane >> 4;
  int rsub = lane >> 3, csub = lane & 7;
  int scsw = (csub ^ rsub) * 8;      // pre-swizzled source col (both-sides rule)

  const unsigned short* kbase = kT + (size_t)bh * NPOS * 64;
  const unsigned short* vbase = vB + (size_t)bh * 64 * NPOS;
  const unsigned short* bptr  = biasP + ((size_t)hh * 1024 + i0 + w * 16) * 1024 + l16 * 4;

  // Q fragments in registers (one q-row per lane)
  int qrow = i0 + w * 16 + l16;
  const unsigned short* qb = qT + ((size_t)bh * NPOS + qrow) * 64 + lh * 8;
  bf16x8 qreg[2];
  qreg[0] = *(const bf16x8*)&qb[0];
  qreg[1] = *(const bf16x8*)&qb[32];

  f32x4 o[5];                        // 0..3 output d-fragments, 4 = softmax denominator
  #pragma unroll
  for (int dt = 0; dt < 5; ++dt) o[dt] = (f32x4){0.f, 0.f, 0.f, 0.f};

  bf16x8 ones;
  {
    u16x8 tmp = {0x3F80, 0x3F80, 0x3F80, 0x3F80, 0x3F80, 0x3F80, 0x3F80, 0x3F80};
    ones = __builtin_bit_cast(bf16x8, tmp);
  }

  // stage tile jj: each of 8 waves stages 1 K-group + 1 V-group (1KB each)
  #define STAGE(Kd, Vd, jj) do {                                                        \
    gload16(&kbase[(size_t)((jj) + w * 8 + rsub) * 64 + scsw], &(Kd)[w * 512]);         \
    gload16(&vbase[(size_t)(w * 8 + rsub) * 1024 + (jj) + scsw], &(Vd)[w * 512]);       \
  } while (0)

  STAGE(Kbuf[0], Vbuf[0], 0);
  __syncthreads();                   // drains prologue staging

  #pragma unroll 1
  for (int t = 0; t < 16; ++t) {
    int j0 = t * 64;
    // issue next tile's staging first: in flight during this tile's compute
    if (t < 15) STAGE(Kbuf[(t + 1) & 1], Vbuf[(t + 1) & 1], j0 + 64);

    const unsigned short* Ks = Kbuf[t & 1];
    const unsigned short* Vs = Vbuf[t & 1];

    // bias preload (overlaps QK^T)
    u16x4 bv4[4];
    #pragma unroll
    for (int r = 0; r < 4; ++r) bv4[r] = *(const u16x4*)&bptr[(lh * 4 + r) * 1024 + j0];

    // ---- QK^T ----
    f32x4 s[4];
    #pragma unroll
    for (int jt = 0; jt < 4; ++jt) s[jt] = (f32x4){0.f, 0.f, 0.f, 0.f};
    #pragma unroll
    for (int ks = 0; ks < 2; ++ks) {
      int koff = ks * 32 + lh * 8;
      #pragma unroll
      for (int jt = 0; jt < 4; ++jt) {
        bf16x8 bk = *(const bf16x8*)&Ks[sw(jt * 16 + l16, koff)];
        s[jt] = __builtin_amdgcn_mfma_f32_16x16x32_bf16(qreg[ks], bk, s[jt], 0, 0, 0);
      }
    }

    // ---- elementwise softmax numerator: P = exp2(s + bias); no max, no cross-lane ----
    #pragma unroll
    for (int r = 0; r < 4; ++r) {
      int rloc = lh * 4 + r;
      #pragma unroll
      for (int jt = 0; jt < 4; ++jt) {
        float pv = __builtin_amdgcn_exp2f(s[jt][r] + bf2f(bv4[r][jt]));
        Ps[w][sw(rloc, jt * 16 + l16)] = f2bf(pv);
      }
    }

    // ---- PV (Ps wave-private: no barrier). o[4] accumulates the denominator ----
    #pragma unroll
    for (int js = 0; js < 2; ++js) {
      int koff = js * 32 + lh * 8;
      bf16x8 pa = *(const bf16x8*)&Ps[w][sw(l16, koff)];
      #pragma unroll
      for (int dt = 0; dt < 4; ++dt) {
        bf16x8 vb = *(const bf16x8*)&Vs[sw(dt * 16 + l16, koff)];
        o[dt] = __builtin_amdgcn_mfma_f32_16x16x32_bf16(pa, vb, o[dt], 0, 0, 0);
      }
      o[4] = __builtin_amdgcn_mfma_f32_16x16x32_bf16(pa, ones, o[4], 0, 0, 0);
    }

    // single barrier per tile: drains next tile's staging + protects buffer reuse
    __syncthreads();
  }

  #pragma unroll
  for (int r = 0; r < 4; ++r) {
    float inv = 1.f / o[4][r];
    int gi = i0 + w * 16 + lh * 4 + r;
    #pragma unroll
    for (int dt = 0; dt < 4; ++dt)
      attnout[((size_t)bb * 1024 + gi) * 512 + hh * 64 + dt * 16 + l16] = f2bf(o[dt][r] * inv);
  }
}

extern "C" void kernel_launch(void* const* d_in, const int* in_sizes, int n_in,
                              void* d_out, int out_size, void* d_ws, size_t ws_size,
                              hipStream_t stream) {
  const float* x     = (const float*)d_in[0];
  const float* gamma = (const float*)d_in[1];
  const float* w_qkv = (const float*)d_in[2];
  const float* w_out = (const float*)d_in[3];
  const float* cw0   = (const float*)d_in[4];
  const float* cb0   = (const float*)d_in[5];
  const float* cw1   = (const float*)d_in[6];
  const float* cb1   = (const float*)d_in[7];
  const float* cw2   = (const float*)d_in[8];
  const float* cb2   = (const float*)d_in[9];
  float* out = (float*)d_out;

  char* ws = (char*)d_ws;
  unsigned short* xnT   = (unsigned short*)(ws + 0);          // 8 MB
  unsigned short* wqb   = (unsigned short*)(ws + 8388608);    // 1.5 MB
  unsigned short* wob   = (unsigned short*)(ws + 9961472);    // 0.5 MB
  unsigned short* qT    = (unsigned short*)(ws + 10485760);   // 8 MB
  unsigned short* kT    = (unsigned short*)(ws + 18874368);   // 8 MB
  unsigned short* vB    = (unsigned short*)(ws + 27262976);   // 8 MB
  float*          table = (float*)(ws + 35651584);            // 128 KB
  unsigned short* biasP = (unsigned short*)(ws + 35782656);   // 16 MB
  unsigned short* aout  = (unsigned short*)(ws + 52559872);   // 8 MB

  setup_kernel<<<5313, 256, 0, stream>>>(w_qkv, w_out, wqb, wob,
                                         cw0, cb0, cw1, cb1, cw2, cb2, table,
                                         x, gamma, xnT);
  bias_expand<<<32768, 256, 0, stream>>>(table, biasP);
  gemm_qkv<<<dim3(64, 12), 256, 0, stream>>>(wqb, xnT, qT, kT, vB);
  attn_kernel<<<dim3(64, 8), 512, 0, stream>>>(qT, kT, vB, biasP, aout);
  gemm_out<<<dim3(64, 8), 256, 0, stream>>>(wob, aout, x, out);
}

// Round 12
// 116.132 us; speedup vs baseline: 1.2853x; 1.1073x over previous
//
#include <hip/hip_runtime.h>
#include <hip/hip_bf16.h>

#define CCH   512
#define BATCH 8
#define NPOS  1024
#define MQKV  1536
#define EPS   1e-5f
#define LOG2E 1.4426950408889634f

typedef __attribute__((ext_vector_type(4))) float f32x4;
typedef __attribute__((ext_vector_type(8))) __bf16 bf16x8;
typedef __attribute__((ext_vector_type(8))) unsigned short u16x8;
typedef __attribute__((ext_vector_type(4))) unsigned short u16x4;

__device__ inline unsigned short f2bf(float f) {
  __hip_bfloat16 h = __float2bfloat16(f);
  return __builtin_bit_cast(unsigned short, h);
}
__device__ inline float bf2f(unsigned short u) {
  return __bfloat162float(__builtin_bit_cast(__hip_bfloat16, u));
}

// LDS xor-swizzle (T2): ushort index within a [row][64] tile.
__device__ inline int sw(int row, int col) { return row * 64 + (col ^ ((row & 7) << 3)); }

// 16B async global->LDS. LDS dest is wave-uniform; HW scatters lane i at dst + i*16B.
__device__ inline void gload16(const void* g, void* l) {
  __builtin_amdgcn_global_load_lds((const __attribute__((address_space(1))) void*)g,
                                   (__attribute__((address_space(3))) void*)l, 16, 0, 0);
}

// ---------------- 1. setup: prep_weights | layernorm ----------------
__global__ __launch_bounds__(256) void setup_kernel(
    const float* __restrict__ wq, const float* __restrict__ wo,
    unsigned short* __restrict__ wqb, unsigned short* __restrict__ wob,
    const float* __restrict__ x, const float* __restrict__ gamma,
    unsigned short* __restrict__ xnT) {
  __shared__ float red[4][32][2];
  __shared__ float gsh[512];
  __shared__ unsigned short obuf[32 * 520];
  int bid = blockIdx.x, tid = threadIdx.x;

  if (bid < 3072) {
    int i = bid * 256 + tid;
    if (i < MQKV * CCH) {
      float v = wq[i];
      if (i < 512 * CCH) v *= 0.125f * LOG2E;   // scores arrive in log2 domain
      wqb[i] = f2bf(v);
    }
    if (i < CCH * CCH) wob[i] = f2bf(wo[i]);
  } else {
    int blk = bid - 3072;                        // 256 = 8 b * 32 pblocks
    int b = blk >> 5, p0 = (blk & 31) * 32;
    int pl = tid & 31, wv = tid >> 6, cg = tid >> 5;
    gsh[tid] = gamma[tid];
    gsh[tid + 256] = gamma[tid + 256];
    const float* xp = x + (size_t)b * CCH * NPOS + p0 + pl;
    float vals[64];
    float s1 = 0.f, s2 = 0.f;
    #pragma unroll
    for (int j = 0; j < 64; ++j) {
      float v = xp[(size_t)(cg + 8 * j) * NPOS];
      vals[j] = v; s1 += v; s2 += v * v;
    }
    s1 += __shfl_xor(s1, 32, 64); s2 += __shfl_xor(s2, 32, 64);
    if ((tid & 63) < 32) { red[wv][pl][0] = s1; red[wv][pl][1] = s2; }
    __syncthreads();
    float t1 = 0.f, t2 = 0.f;
    #pragma unroll
    for (int w2i = 0; w2i < 4; ++w2i) { t1 += red[w2i][pl][0]; t2 += red[w2i][pl][1]; }
    float mean = t1 * (1.f / 512.f);
    float var = t2 * (1.f / 512.f) - mean * mean;
    float rstd = rsqrtf(var + EPS);
    #pragma unroll
    for (int j = 0; j < 64; ++j) {
      int c = cg + 8 * j;
      obuf[pl * 520 + c] = f2bf((vals[j] - mean) * rstd * gsh[c]);
    }
    __syncthreads();
    unsigned short* orow = xnT + ((size_t)b * NPOS + p0) * 512;
    #pragma unroll
    for (int i = 0; i < 8; ++i) {
      int c2 = tid + i * 256;
      int pp = c2 >> 6, ch = c2 & 63;
      *(u16x8*)&orow[(size_t)pp * 512 + ch * 8] = *(const u16x8*)&obuf[pp * 520 + ch * 8];
    }
  }
}

// ---------------- 2. CPB table with LDS-cached w1/w2 ----------------
// 256 blocks x 8 passes x 2 d0. w1 staged coalesced once per block at stride 129
// (bank = (t+c)%32 -> conflict-free); layer-3 parallel across 128 lanes + shfl reduce.
__global__ __launch_bounds__(256) void cpb_kernel(
    const float* __restrict__ w0, const float* __restrict__ b0,
    const float* __restrict__ w1, const float* __restrict__ b1,
    const float* __restrict__ w2, const float* __restrict__ b2,
    float* __restrict__ table) {
  __shared__ float w1s[128 * 129];   // 66048 B
  __shared__ float w2s[8 * 128];
  __shared__ float sh1[2][128];
  __shared__ float sh2[2][128];
  int tid = threadIdx.x;
  #pragma unroll
  for (int i = 0; i < 64; ++i) {
    int idx = i * 256 + tid;
    w1s[(idx >> 7) * 129 + (idx & 127)] = w1[idx];
  }
  #pragma unroll
  for (int i = 0; i < 4; ++i) {
    int idx = i * 256 + tid;
    w2s[idx] = w2[idx];
  }
  int sub = tid >> 7, t = tid & 127;
  float w00 = w0[t * 2 + 0], w01 = w0[t * 2 + 1], bb0 = b0[t], bb1 = b1[t];
  int hh = t >> 4, k16 = t & 15;
  float b2h = b2[hh];
  __syncthreads();

  #pragma unroll 1
  for (int pass = 0; pass < 8; ++pass) {
    int d0 = (blockIdx.x * 8 + pass) * 2 + sub;
    bool ok = d0 < 3969;
    int d0c = ok ? d0 : 0;
    int dy = d0c / 63 - 31, dx = d0c % 63 - 31;
    float r0 = (dy > 0 ? 1.f : (dy < 0 ? -1.f : 0.f)) * logf(fabsf((float)dy) + 1.f);
    float r1 = (dx > 0 ? 1.f : (dx < 0 ? -1.f : 0.f)) * logf(fabsf((float)dx) + 1.f);
    float h0 = r0 * w00 + r1 * w01 + bb0;
    sh1[sub][t] = (h0 >= 0.f) ? h0 : 0.1f * h0;
    __syncthreads();
    float a = bb1;
    #pragma unroll 8
    for (int c = 0; c < 128; ++c) a += sh1[sub][c] * w1s[t * 129 + c];
    sh2[sub][t] = (a >= 0.f) ? a : 0.1f * a;
    __syncthreads();
    float o = 0.f;
    #pragma unroll
    for (int c = 0; c < 8; ++c) o += sh2[sub][k16 * 8 + c] * w2s[hh * 128 + k16 * 8 + c];
    #pragma unroll
    for (int mm = 1; mm < 16; mm <<= 1) o += __shfl_xor(o, mm, 64);
    if (k16 == 0 && ok) table[hh * 3969 + d0] = (o + b2h) * LOG2E;
    __syncthreads();   // protect sh1/sh2 before next pass
  }
}

// ---------------- 3. expand bias, fragment-permuted: [h][i][jtile(16)][l16*4+jt] ----------------
__global__ void bias_expand(const float* __restrict__ table, unsigned short* __restrict__ biasP) {
  int idx = blockIdx.x * 256 + threadIdx.x;   // 8*1024*1024 total, idx == output address
  int h = idx >> 20;
  int i = (idx >> 10) & 1023;
  int blk = (idx >> 6) & 15;
  int q = idx & 63;
  int l16 = q >> 2, jt = q & 3;
  int j = blk * 64 + jt * 16 + l16;
  int dy = (i >> 5) - (j >> 5) + 31;
  int dx = (i & 31) - (j & 31) + 31;
  biasP[idx] = f2bf(table[h * 3969 + dy * 63 + dx]);
}

// ---------------- 4. qkv GEMM: qkv = wqb * xnT^T, LDS-bounced scatter epilogue ----------------
__global__ __launch_bounds__(256) void gemm_qkv(const unsigned short* __restrict__ Ag,
                                                const unsigned short* __restrict__ Bg,
                                                unsigned short* __restrict__ qT,
                                                unsigned short* __restrict__ kT,
                                                unsigned short* __restrict__ vB) {
  __shared__ unsigned short smem[2 * 128 * 64];   // As | Bs; reused as 128x128 C-tile
  unsigned short* As = smem;
  unsigned short* Bs = smem + 128 * 64;
  int tid = threadIdx.x;
  int by = blockIdx.y;
  int m0 = by * 128, nn0 = blockIdx.x * 128;
  int wave = tid >> 6, lane = tid & 63;
  int wm = wave >> 1, wn = wave & 1;
  int l16 = lane & 15, lh = lane >> 4;
  int rsub = lane >> 3, csub = lane & 7;
  int scsw = (csub ^ rsub) * 8;                   // pre-swizzled source col (ushorts)
  f32x4 acc[4][4];
  #pragma unroll
  for (int it = 0; it < 4; ++it)
    #pragma unroll
    for (int jt = 0; jt < 4; ++jt) acc[it][jt] = (f32x4){0.f, 0.f, 0.f, 0.f};

  for (int k0 = 0; k0 < 512; k0 += 64) {
    #pragma unroll
    for (int i = 0; i < 4; ++i) {
      int grp = wave * 4 + i;                     // 16 groups of 8 rows
      int row = grp * 8 + rsub;
      gload16(&Ag[(size_t)(m0 + row) * 512 + k0 + scsw], &As[grp * 512]);
      gload16(&Bg[(size_t)(nn0 + row) * 512 + k0 + scsw], &Bs[grp * 512]);
    }
    __syncthreads();
    #pragma unroll
    for (int ks = 0; ks < 2; ++ks) {
      int koff = ks * 32 + lh * 8;
      bf16x8 a[4], b[4];
      #pragma unroll
      for (int it = 0; it < 4; ++it) a[it] = *(const bf16x8*)&As[sw(wm * 64 + it * 16 + l16, koff)];
      #pragma unroll
      for (int jt = 0; jt < 4; ++jt) b[jt] = *(const bf16x8*)&Bs[sw(wn * 64 + jt * 16 + l16, koff)];
      #pragma unroll
      for (int it = 0; it < 4; ++it)
        #pragma unroll
        for (int jt = 0; jt < 4; ++jt)
          acc[it][jt] = __builtin_amdgcn_mfma_f32_16x16x32_bf16(a[it], b[jt], acc[it][jt], 0, 0, 0);
    }
    __syncthreads();
  }

  // ---- LDS-bounced coalesced epilogue ----
  int sel = by >> 2;                 // 0:q 1:k 2:v
  int hh0 = (by & 3) * 2;
  int bb = nn0 >> 10, p0 = nn0 & 1023;
  unsigned short* Cs = smem;         // 128x128 ushort = 32 KB
  if (sel < 2) {
    #pragma unroll
    for (int it = 0; it < 4; ++it)
      #pragma unroll
      for (int jt = 0; jt < 4; ++jt) {
        int nnl = wn * 64 + jt * 16 + l16;
        int mb = wm * 64 + it * 16 + lh * 4;
        #pragma unroll
        for (int r = 0; r < 4; ++r)
          Cs[nnl * 128 + ((mb + r) ^ ((nnl & 7) << 4))] = f2bf(acc[it][jt][r]);
      }
    __syncthreads();
    unsigned short* dst = (sel == 0) ? qT : kT;
    #pragma unroll
    for (int i = 0; i < 8; ++i) {
      int c = tid + i * 256;
      int hl = c >> 10, p = (c >> 3) & 127, ch = c & 7;
      int mb = hl * 64 + ch * 8;
      u16x8 val = *(u16x8*)&Cs[p * 128 + (mb ^ ((p & 7) << 4))];
      int bh = bb * 8 + hh0 + hl;
      *(u16x8*)&dst[((size_t)bh * 1024 + p0 + p) * 64 + ch * 8] = val;
    }
  } else {
    #pragma unroll
    for (int it = 0; it < 4; ++it)
      #pragma unroll
      for (int jt = 0; jt < 4; ++jt) {
        int nnl = wn * 64 + jt * 16 + l16;
        int mb = wm * 64 + it * 16 + lh * 4;
        #pragma unroll
        for (int r = 0; r < 4; ++r)
          Cs[(mb + r) * 128 + (nnl ^ (((mb + r) & 7) << 4))] = f2bf(acc[it][jt][r]);
      }
    __syncthreads();
    #pragma unroll
    for (int i = 0; i < 8; ++i) {
      int c = tid + i * 256;
      int mloc = c >> 4, ch = c & 15;
      u16x8 val = *(u16x8*)&Cs[mloc * 128 + ((ch * 8) ^ ((mloc & 7) << 4))];
      int d = mloc & 63, hl = mloc >> 6;
      int bh = bb * 8 + hh0 + hl;
      *(u16x8*)&vB[((size_t)bh * 64 + d) * 1024 + p0 + ch * 8] = val;
    }
  }
}

// ---------------- 5. out GEMM: 64x128 tiles -> 512 blocks (2 blocks/CU) ----------------
__global__ __launch_bounds__(256) void gemm_out(const unsigned short* __restrict__ Ag,
                                                const unsigned short* __restrict__ Bg,
                                                const float* __restrict__ xres,
                                                float* __restrict__ yout) {
  __shared__ unsigned short As[64 * 64];    // 8 KB
  __shared__ unsigned short Bs[128 * 64];   // 16 KB
  int tid = threadIdx.x;
  int m0 = blockIdx.y * 64, nn0 = blockIdx.x * 128;
  int wave = tid >> 6, lane = tid & 63;
  int wm = wave >> 1, wn = wave & 1;        // 2x2 waves, each 32m x 64n
  int l16 = lane & 15, lh = lane >> 4;
  int rsub = lane >> 3, csub = lane & 7;
  int scsw = (csub ^ rsub) * 8;
  f32x4 acc[2][4];
  #pragma unroll
  for (int it = 0; it < 2; ++it)
    #pragma unroll
    for (int jt = 0; jt < 4; ++jt) acc[it][jt] = (f32x4){0.f, 0.f, 0.f, 0.f};

  for (int k0 = 0; k0 < 512; k0 += 64) {
    #pragma unroll
    for (int i = 0; i < 2; ++i) {           // A: 8 groups of 8 rows, 2 per wave
      int grp = wave * 2 + i;
      gload16(&Ag[(size_t)(m0 + grp * 8 + rsub) * 512 + k0 + scsw], &As[grp * 512]);
    }
    #pragma unroll
    for (int i = 0; i < 4; ++i) {           // B: 16 groups, 4 per wave
      int grp = wave * 4 + i;
      gload16(&Bg[(size_t)(nn0 + grp * 8 + rsub) * 512 + k0 + scsw], &Bs[grp * 512]);
    }
    __syncthreads();
    #pragma unroll
    for (int ks = 0; ks < 2; ++ks) {
      int koff = ks * 32 + lh * 8;
      bf16x8 a[2], b[4];
      #pragma unroll
      for (int it = 0; it < 2; ++it) a[it] = *(const bf16x8*)&As[sw(wm * 32 + it * 16 + l16, koff)];
      #pragma unroll
      for (int jt = 0; jt < 4; ++jt) b[jt] = *(const bf16x8*)&Bs[sw(wn * 64 + jt * 16 + l16, koff)];
      #pragma unroll
      for (int it = 0; it < 2; ++it)
        #pragma unroll
        for (int jt = 0; jt < 4; ++jt)
          acc[it][jt] = __builtin_amdgcn_mfma_f32_16x16x32_bf16(a[it], b[jt], acc[it][jt], 0, 0, 0);
    }
    __syncthreads();
  }

  #pragma unroll
  for (int it = 0; it < 2; ++it) {
    int mbase = m0 + wm * 32 + it * 16 + lh * 4;
    #pragma unroll
    for (int jt = 0; jt < 4; ++jt) {
      int nn = nn0 + wn * 64 + jt * 16 + l16;
      int bb = nn >> 10, p = nn & 1023;
      #pragma unroll
      for (int r = 0; r < 4; ++r) {
        size_t addr = ((size_t)bb * 512 + mbase + r) * 1024 + p;
        yout[addr] = acc[it][jt][r] + xres[addr];
      }
    }
  }
}

// ---------------- 6. flash attention: 8 waves / 128 q-rows, bh-fastest grid ----------------
__global__ __launch_bounds__(512) void attn_kernel(const unsigned short* __restrict__ qT,
                                                   const unsigned short* __restrict__ kT,
                                                   const unsigned short* __restrict__ vB,
                                                   const unsigned short* __restrict__ biasP,
                                                   unsigned short* __restrict__ attnout) {
  __shared__ unsigned short Kbuf[2][64 * 64];
  __shared__ unsigned short Vbuf[2][64 * 64];
  __shared__ unsigned short Ps[8][16 * 64];
  int tid = threadIdx.x;
  int bh = blockIdx.x;               // bh-fastest: XCD = bh%8
  int i0 = blockIdx.y * 128;
  int hh = bh & 7, bb = bh >> 3;
  int w = tid >> 6, lane = tid & 63, l16 = lane & 15, lh = lane >> 4;
  int rsub = lane >> 3, csub = lane & 7;
  int scsw = (csub ^ rsub) * 8;      // pre-swizzled source col (both-sides rule)

  const unsigned short* kbase = kT + (size_t)bh * NPOS * 64;
  const unsigned short* vbase = vB + (size_t)bh * 64 * NPOS;
  const unsigned short* bptr  = biasP + ((size_t)hh * 1024 + i0 + w * 16) * 1024 + l16 * 4;

  // Q fragments in registers (one q-row per lane)
  int qrow = i0 + w * 16 + l16;
  const unsigned short* qb = qT + ((size_t)bh * NPOS + qrow) * 64 + lh * 8;
  bf16x8 qreg[2];
  qreg[0] = *(const bf16x8*)&qb[0];
  qreg[1] = *(const bf16x8*)&qb[32];

  f32x4 o[5];                        // 0..3 output d-fragments, 4 = softmax denominator
  #pragma unroll
  for (int dt = 0; dt < 5; ++dt) o[dt] = (f32x4){0.f, 0.f, 0.f, 0.f};

  bf16x8 ones;
  {
    u16x8 tmp = {0x3F80, 0x3F80, 0x3F80, 0x3F80, 0x3F80, 0x3F80, 0x3F80, 0x3F80};
    ones = __builtin_bit_cast(bf16x8, tmp);
  }

  // stage tile jj: each of 8 waves stages 1 K-group + 1 V-group (1KB each)
  #define STAGE(Kd, Vd, jj) do {                                                        \
    gload16(&kbase[(size_t)((jj) + w * 8 + rsub) * 64 + scsw], &(Kd)[w * 512]);         \
    gload16(&vbase[(size_t)(w * 8 + rsub) * 1024 + (jj) + scsw], &(Vd)[w * 512]);       \
  } while (0)

  STAGE(Kbuf[0], Vbuf[0], 0);
  __syncthreads();                   // drains prologue staging

  #pragma unroll 1
  for (int t = 0; t < 16; ++t) {
    int j0 = t * 64;
    // issue next tile's staging first: in flight during this tile's compute
    if (t < 15) STAGE(Kbuf[(t + 1) & 1], Vbuf[(t + 1) & 1], j0 + 64);

    const unsigned short* Ks = Kbuf[t & 1];
    const unsigned short* Vs = Vbuf[t & 1];

    // bias preload (overlaps QK^T)
    u16x4 bv4[4];
    #pragma unroll
    for (int r = 0; r < 4; ++r) bv4[r] = *(const u16x4*)&bptr[(lh * 4 + r) * 1024 + j0];

    // ---- QK^T ----
    f32x4 s[4];
    #pragma unroll
    for (int jt = 0; jt < 4; ++jt) s[jt] = (f32x4){0.f, 0.f, 0.f, 0.f};
    #pragma unroll
    for (int ks = 0; ks < 2; ++ks) {
      int koff = ks * 32 + lh * 8;
      #pragma unroll
      for (int jt = 0; jt < 4; ++jt) {
        bf16x8 bk = *(const bf16x8*)&Ks[sw(jt * 16 + l16, koff)];
        s[jt] = __builtin_amdgcn_mfma_f32_16x16x32_bf16(qreg[ks], bk, s[jt], 0, 0, 0);
      }
    }

    // ---- elementwise softmax numerator: P = exp2(s + bias); no max, no cross-lane ----
    #pragma unroll
    for (int r = 0; r < 4; ++r) {
      int rloc = lh * 4 + r;
      #pragma unroll
      for (int jt = 0; jt < 4; ++jt) {
        float pv = __builtin_amdgcn_exp2f(s[jt][r] + bf2f(bv4[r][jt]));
        Ps[w][sw(rloc, jt * 16 + l16)] = f2bf(pv);
      }
    }

    // ---- PV (Ps wave-private: no barrier). o[4] accumulates the denominator ----
    #pragma unroll
    for (int js = 0; js < 2; ++js) {
      int koff = js * 32 + lh * 8;
      bf16x8 pa = *(const bf16x8*)&Ps[w][sw(l16, koff)];
      #pragma unroll
      for (int dt = 0; dt < 4; ++dt) {
        bf16x8 vb = *(const bf16x8*)&Vs[sw(dt * 16 + l16, koff)];
        o[dt] = __builtin_amdgcn_mfma_f32_16x16x32_bf16(pa, vb, o[dt], 0, 0, 0);
      }
      o[4] = __builtin_amdgcn_mfma_f32_16x16x32_bf16(pa, ones, o[4], 0, 0, 0);
    }

    // single barrier per tile: drains next tile's staging + protects buffer reuse
    __syncthreads();
  }

  #pragma unroll
  for (int r = 0; r < 4; ++r) {
    float inv = 1.f / o[4][r];
    int gi = i0 + w * 16 + lh * 4 + r;
    #pragma unroll
    for (int dt = 0; dt < 4; ++dt)
      attnout[((size_t)bb * 1024 + gi) * 512 + hh * 64 + dt * 16 + l16] = f2bf(o[dt][r] * inv);
  }
}

extern "C" void kernel_launch(void* const* d_in, const int* in_sizes, int n_in,
                              void* d_out, int out_size, void* d_ws, size_t ws_size,
                              hipStream_t stream) {
  const float* x     = (const float*)d_in[0];
  const float* gamma = (const float*)d_in[1];
  const float* w_qkv = (const float*)d_in[2];
  const float* w_out = (const float*)d_in[3];
  const float* cw0   = (const float*)d_in[4];
  const float* cb0   = (const float*)d_in[5];
  const float* cw1   = (const float*)d_in[6];
  const float* cb1   = (const float*)d_in[7];
  const float* cw2   = (const float*)d_in[8];
  const float* cb2   = (const float*)d_in[9];
  float* out = (float*)d_out;

  char* ws = (char*)d_ws;
  unsigned short* xnT   = (unsigned short*)(ws + 0);          // 8 MB
  unsigned short* wqb   = (unsigned short*)(ws + 8388608);    // 1.5 MB
  unsigned short* wob   = (unsigned short*)(ws + 9961472);    // 0.5 MB
  unsigned short* qT    = (unsigned short*)(ws + 10485760);   // 8 MB
  unsigned short* kT    = (unsigned short*)(ws + 18874368);   // 8 MB
  unsigned short* vB    = (unsigned short*)(ws + 27262976);   // 8 MB
  float*          table = (float*)(ws + 35651584);            // 128 KB
  unsigned short* biasP = (unsigned short*)(ws + 35782656);   // 16 MB
  unsigned short* aout  = (unsigned short*)(ws + 52559872);   // 8 MB

  cpb_kernel<<<256, 256, 0, stream>>>(cw0, cb0, cw1, cb1, cw2, cb2, table);
  setup_kernel<<<3328, 256, 0, stream>>>(w_qkv, w_out, wqb, wob, x, gamma, xnT);
  bias_expand<<<32768, 256, 0, stream>>>(table, biasP);
  gemm_qkv<<<dim3(64, 12), 256, 0, stream>>>(wqb, xnT, qT, kT, vB);
  attn_kernel<<<dim3(64, 8), 512, 0, stream>>>(qT, kT, vB, biasP, aout);
  gemm_out<<<dim3(64, 8), 256, 0, stream>>>(wob, aout, x, out);
}

// Round 14
// 110.204 us; speedup vs baseline: 1.3545x; 1.0538x over previous
//
#include <hip/hip_runtime.h>
#include <hip/hip_bf16.h>

#define CCH   512
#define BATCH 8
#define NPOS  1024
#define MQKV  1536
#define EPS   1e-5f
#define LOG2E 1.4426950408889634f

typedef __attribute__((ext_vector_type(4))) float f32x4;
typedef __attribute__((ext_vector_type(8))) __bf16 bf16x8;
typedef __attribute__((ext_vector_type(8))) unsigned short u16x8;
typedef __attribute__((ext_vector_type(4))) unsigned short u16x4;

__device__ inline unsigned short f2bf(float f) {
  __hip_bfloat16 h = __float2bfloat16(f);
  return __builtin_bit_cast(unsigned short, h);
}
__device__ inline float bf2f(unsigned short u) {
  return __bfloat162float(__builtin_bit_cast(__hip_bfloat16, u));
}

// LDS xor-swizzle for [row][64] ushort tiles (128B rows): 2-way (free) aliasing.
__device__ inline int sw(int row, int col) { return row * 64 + (col ^ ((row & 7) << 3)); }
// LDS xor-swizzle for [row][32] ushort tiles (64B rows): chunk ^= (row ^ row>>2)&3.
__device__ inline int sw32(int row, int lh) {
  return row * 32 + ((lh ^ ((row ^ (row >> 2)) & 3)) << 3);
}

// 16B async global->LDS. LDS dest is wave-uniform; HW scatters lane i at dst + i*16B.
__device__ inline void gload16(const void* g, void* l) {
  __builtin_amdgcn_global_load_lds((const __attribute__((address_space(1))) void*)g,
                                   (__attribute__((address_space(3))) void*)l, 16, 0, 0);
}

// ---------------- 1. setup: prep_weights | layernorm ----------------
__global__ __launch_bounds__(256) void setup_kernel(
    const float* __restrict__ wq, const float* __restrict__ wo,
    unsigned short* __restrict__ wqb, unsigned short* __restrict__ wob,
    const float* __restrict__ x, const float* __restrict__ gamma,
    unsigned short* __restrict__ xnT) {
  __shared__ float red[4][32][2];
  __shared__ float gsh[512];
  __shared__ unsigned short obuf[32 * 520];
  int bid = blockIdx.x, tid = threadIdx.x;

  if (bid < 3072) {
    int i = bid * 256 + tid;
    if (i < MQKV * CCH) {
      float v = wq[i];
      if (i < 512 * CCH) v *= 0.125f * LOG2E;   // scores arrive in log2 domain
      wqb[i] = f2bf(v);
    }
    if (i < CCH * CCH) wob[i] = f2bf(wo[i]);
  } else {
    int blk = bid - 3072;                        // 256 = 8 b * 32 pblocks
    int b = blk >> 5, p0 = (blk & 31) * 32;
    int pl = tid & 31, wv = tid >> 6, cg = tid >> 5;
    gsh[tid] = gamma[tid];
    gsh[tid + 256] = gamma[tid + 256];
    const float* xp = x + (size_t)b * CCH * NPOS + p0 + pl;
    float vals[64];
    float s1 = 0.f, s2 = 0.f;
    #pragma unroll
    for (int j = 0; j < 64; ++j) {
      float v = xp[(size_t)(cg + 8 * j) * NPOS];
      vals[j] = v; s1 += v; s2 += v * v;
    }
    s1 += __shfl_xor(s1, 32, 64); s2 += __shfl_xor(s2, 32, 64);
    if ((tid & 63) < 32) { red[wv][pl][0] = s1; red[wv][pl][1] = s2; }
    __syncthreads();
    float t1 = 0.f, t2 = 0.f;
    #pragma unroll
    for (int w2i = 0; w2i < 4; ++w2i) { t1 += red[w2i][pl][0]; t2 += red[w2i][pl][1]; }
    float mean = t1 * (1.f / 512.f);
    float var = t2 * (1.f / 512.f) - mean * mean;
    float rstd = rsqrtf(var + EPS);
    #pragma unroll
    for (int j = 0; j < 64; ++j) {
      int c = cg + 8 * j;
      obuf[pl * 520 + c] = f2bf((vals[j] - mean) * rstd * gsh[c]);
    }
    __syncthreads();
    unsigned short* orow = xnT + ((size_t)b * NPOS + p0) * 512;
    #pragma unroll
    for (int i = 0; i < 8; ++i) {
      int c2 = tid + i * 256;
      int pp = c2 >> 6, ch = c2 & 63;
      *(u16x8*)&orow[(size_t)pp * 512 + ch * 8] = *(const u16x8*)&obuf[pp * 520 + ch * 8];
    }
  }
}

// ---------------- 2. CPB table with LDS-cached w1/w2 ----------------
__global__ __launch_bounds__(256) void cpb_kernel(
    const float* __restrict__ w0, const float* __restrict__ b0,
    const float* __restrict__ w1, const float* __restrict__ b1,
    const float* __restrict__ w2, const float* __restrict__ b2,
    float* __restrict__ table) {
  __shared__ float w1s[128 * 129];   // 66048 B
  __shared__ float w2s[8 * 128];
  __shared__ float sh1[2][128];
  __shared__ float sh2[2][128];
  int tid = threadIdx.x;
  #pragma unroll
  for (int i = 0; i < 64; ++i) {
    int idx = i * 256 + tid;
    w1s[(idx >> 7) * 129 + (idx & 127)] = w1[idx];
  }
  #pragma unroll
  for (int i = 0; i < 4; ++i) {
    int idx = i * 256 + tid;
    w2s[idx] = w2[idx];
  }
  int sub = tid >> 7, t = tid & 127;
  float w00 = w0[t * 2 + 0], w01 = w0[t * 2 + 1], bb0 = b0[t], bb1 = b1[t];
  int hh = t >> 4, k16 = t & 15;
  float b2h = b2[hh];
  __syncthreads();

  #pragma unroll 1
  for (int pass = 0; pass < 8; ++pass) {
    int d0 = (blockIdx.x * 8 + pass) * 2 + sub;
    bool ok = d0 < 3969;
    int d0c = ok ? d0 : 0;
    int dy = d0c / 63 - 31, dx = d0c % 63 - 31;
    float r0 = (dy > 0 ? 1.f : (dy < 0 ? -1.f : 0.f)) * logf(fabsf((float)dy) + 1.f);
    float r1 = (dx > 0 ? 1.f : (dx < 0 ? -1.f : 0.f)) * logf(fabsf((float)dx) + 1.f);
    float h0 = r0 * w00 + r1 * w01 + bb0;
    sh1[sub][t] = (h0 >= 0.f) ? h0 : 0.1f * h0;
    __syncthreads();
    float a = bb1;
    #pragma unroll 8
    for (int c = 0; c < 128; ++c) a += sh1[sub][c] * w1s[t * 129 + c];
    sh2[sub][t] = (a >= 0.f) ? a : 0.1f * a;
    __syncthreads();
    float o = 0.f;
    #pragma unroll
    for (int c = 0; c < 8; ++c) o += sh2[sub][k16 * 8 + c] * w2s[hh * 128 + k16 * 8 + c];
    #pragma unroll
    for (int mm = 1; mm < 16; mm <<= 1) o += __shfl_xor(o, mm, 64);
    if (k16 == 0 && ok) table[hh * 3969 + d0] = (o + b2h) * LOG2E;
    __syncthreads();   // protect sh1/sh2 before next pass
  }
}

// ---------------- 3. expand bias, fragment-permuted, u16x8 stores ----------------
__global__ void bias_expand(const float* __restrict__ table, unsigned short* __restrict__ biasP) {
  int base = (blockIdx.x * 256 + threadIdx.x) * 8;   // 8M total / 8 per thread
  int h = base >> 20;
  int i = (base >> 10) & 1023;
  int blk = (base >> 6) & 15;
  int q0 = base & 63;
  int ib = i >> 5, il = i & 31;
  u16x8 outv;
  #pragma unroll
  for (int e = 0; e < 8; ++e) {
    int q = q0 + e;
    int l16 = q >> 2, jt = q & 3;
    int j = blk * 64 + jt * 16 + l16;
    int dy = ib - (j >> 5) + 31;
    int dx = il - (j & 31) + 31;
    outv[e] = f2bf(table[h * 3969 + dy * 63 + dx]);
  }
  *(u16x8*)&biasP[base] = outv;
}

// ---------------- 4. qkv GEMM: BK=32 double-buffered 2-phase pipeline ----------------
__global__ __launch_bounds__(256) void gemm_qkv(const unsigned short* __restrict__ Ag,
                                                const unsigned short* __restrict__ Bg,
                                                unsigned short* __restrict__ qT,
                                                unsigned short* __restrict__ kT,
                                                unsigned short* __restrict__ vB) {
  __shared__ unsigned short smem[16384];          // 32 KB: As0|As1|Bs0|Bs1, reused as C-tile
  int tid = threadIdx.x;
  int by = blockIdx.y;
  int m0 = by * 128, nn0 = blockIdx.x * 128;
  int wave = tid >> 6, lane = tid & 63;
  int wm = wave >> 1, wn = wave & 1;
  int l16 = lane & 15, lh = lane >> 4;
  int r4 = lane >> 2, c4 = lane & 3;
  int csw = ((c4 ^ (r4 & 3) ^ ((lane >> 4) & 3))) << 3;   // pre-swizzled source col
  f32x4 acc[4][4];
  #pragma unroll
  for (int it = 0; it < 4; ++it)
    #pragma unroll
    for (int jt = 0; jt < 4; ++jt) acc[it][jt] = (f32x4){0.f, 0.f, 0.f, 0.f};

  // stage K-step at col k0 into buffer bsel: 8 row-groups of 16, 2 per wave per array
  #define GSTAGE(bsel, k0) do {                                                               \
    _Pragma("unroll")                                                                         \
    for (int i_ = 0; i_ < 2; ++i_) {                                                          \
      int grp_ = wave * 2 + i_;                                                               \
      int row_ = grp_ * 16 + r4;                                                              \
      gload16(&Ag[(size_t)(m0 + row_) * 512 + (k0) + csw], smem + (bsel) * 4096 + grp_ * 512);\
      gload16(&Bg[(size_t)(nn0 + row_) * 512 + (k0) + csw],                                   \
              smem + 8192 + (bsel) * 4096 + grp_ * 512);                                      \
    }                                                                                         \
  } while (0)

  GSTAGE(0, 0);
  __syncthreads();
  #pragma unroll 1
  for (int k = 0; k < 16; ++k) {
    if (k < 15) GSTAGE((k + 1) & 1, (k + 1) * 32);
    const unsigned short* As = smem + (k & 1) * 4096;
    const unsigned short* Bs = smem + 8192 + (k & 1) * 4096;
    bf16x8 a[4], b[4];
    #pragma unroll
    for (int it = 0; it < 4; ++it) a[it] = *(const bf16x8*)&As[sw32(wm * 64 + it * 16 + l16, lh)];
    #pragma unroll
    for (int jt = 0; jt < 4; ++jt) b[jt] = *(const bf16x8*)&Bs[sw32(wn * 64 + jt * 16 + l16, lh)];
    __builtin_amdgcn_s_setprio(1);
    #pragma unroll
    for (int it = 0; it < 4; ++it)
      #pragma unroll
      for (int jt = 0; jt < 4; ++jt)
        acc[it][jt] = __builtin_amdgcn_mfma_f32_16x16x32_bf16(a[it], b[jt], acc[it][jt], 0, 0, 0);
    __builtin_amdgcn_s_setprio(0);
    __syncthreads();   // staging (k+1) complete + buffer (k&1) free for k+2's staging
  }

  // ---- LDS-bounced coalesced epilogue ----
  int sel = by >> 2;                 // 0:q 1:k 2:v
  int hh0 = (by & 3) * 2;
  int bb = nn0 >> 10, p0 = nn0 & 1023;
  unsigned short* Cs = smem;         // 128x128 ushort = 32 KB
  if (sel < 2) {
    #pragma unroll
    for (int it = 0; it < 4; ++it)
      #pragma unroll
      for (int jt = 0; jt < 4; ++jt) {
        int nnl = wn * 64 + jt * 16 + l16;
        int mb = wm * 64 + it * 16 + lh * 4;
        #pragma unroll
        for (int r = 0; r < 4; ++r)
          Cs[nnl * 128 + ((mb + r) ^ ((nnl & 7) << 4))] = f2bf(acc[it][jt][r]);
      }
    __syncthreads();
    unsigned short* dst = (sel == 0) ? qT : kT;
    #pragma unroll
    for (int i = 0; i < 8; ++i) {
      int c = tid + i * 256;
      int hl = c >> 10, p = (c >> 3) & 127, ch = c & 7;
      int mb = hl * 64 + ch * 8;
      u16x8 val = *(u16x8*)&Cs[p * 128 + (mb ^ ((p & 7) << 4))];
      int bh = bb * 8 + hh0 + hl;
      *(u16x8*)&dst[((size_t)bh * 1024 + p0 + p) * 64 + ch * 8] = val;
    }
  } else {
    #pragma unroll
    for (int it = 0; it < 4; ++it)
      #pragma unroll
      for (int jt = 0; jt < 4; ++jt) {
        int nnl = wn * 64 + jt * 16 + l16;
        int mb = wm * 64 + it * 16 + lh * 4;
        #pragma unroll
        for (int r = 0; r < 4; ++r)
          Cs[(mb + r) * 128 + (nnl ^ (((mb + r) & 7) << 4))] = f2bf(acc[it][jt][r]);
      }
    __syncthreads();
    #pragma unroll
    for (int i = 0; i < 8; ++i) {
      int c = tid + i * 256;
      int mloc = c >> 4, ch = c & 15;
      u16x8 val = *(u16x8*)&Cs[mloc * 128 + ((ch * 8) ^ ((mloc & 7) << 4))];
      int d = mloc & 63, hl = mloc >> 6;
      int bh = bb * 8 + hh0 + hl;
      *(u16x8*)&vB[((size_t)bh * 64 + d) * 1024 + p0 + ch * 8] = val;
    }
  }
}

// ---------------- 5. out GEMM: 64x128 tiles, BK=32 2-phase pipeline ----------------
__global__ __launch_bounds__(256) void gemm_out(const unsigned short* __restrict__ Ag,
                                                const unsigned short* __restrict__ Bg,
                                                const float* __restrict__ xres,
                                                float* __restrict__ yout) {
  __shared__ unsigned short smem[12288];          // 24 KB: As0|As1 @0,2048; Bs0|Bs1 @4096,8192
  int tid = threadIdx.x;
  int m0 = blockIdx.y * 64, nn0 = blockIdx.x * 128;
  int wave = tid >> 6, lane = tid & 63;
  int wm = wave >> 1, wn = wave & 1;        // 2x2 waves, each 32m x 64n
  int l16 = lane & 15, lh = lane >> 4;
  int r4 = lane >> 2, c4 = lane & 3;
  int csw = ((c4 ^ (r4 & 3) ^ ((lane >> 4) & 3))) << 3;
  f32x4 acc[2][4];
  #pragma unroll
  for (int it = 0; it < 2; ++it)
    #pragma unroll
    for (int jt = 0; jt < 4; ++jt) acc[it][jt] = (f32x4){0.f, 0.f, 0.f, 0.f};

  #define OSTAGE(bsel, k0) do {                                                               \
    {                                                                                         \
      int row_ = wave * 16 + r4;                                                              \
      gload16(&Ag[(size_t)(m0 + row_) * 512 + (k0) + csw],                                    \
              smem + (bsel) * 2048 + wave * 512);                                             \
    }                                                                                         \
    _Pragma("unroll")                                                                         \
    for (int i_ = 0; i_ < 2; ++i_) {                                                          \
      int grp_ = wave * 2 + i_;                                                               \
      int row_ = grp_ * 16 + r4;                                                              \
      gload16(&Bg[(size_t)(nn0 + row_) * 512 + (k0) + csw],                                   \
              smem + 4096 + (bsel) * 4096 + grp_ * 512);                                      \
    }                                                                                         \
  } while (0)

  OSTAGE(0, 0);
  __syncthreads();
  #pragma unroll 1
  for (int k = 0; k < 16; ++k) {
    if (k < 15) OSTAGE((k + 1) & 1, (k + 1) * 32);
    const unsigned short* As = smem + (k & 1) * 2048;
    const unsigned short* Bs = smem + 4096 + (k & 1) * 4096;
    bf16x8 a[2], b[4];
    #pragma unroll
    for (int it = 0; it < 2; ++it) a[it] = *(const bf16x8*)&As[sw32(wm * 32 + it * 16 + l16, lh)];
    #pragma unroll
    for (int jt = 0; jt < 4; ++jt) b[jt] = *(const bf16x8*)&Bs[sw32(wn * 64 + jt * 16 + l16, lh)];
    __builtin_amdgcn_s_setprio(1);
    #pragma unroll
    for (int it = 0; it < 2; ++it)
      #pragma unroll
      for (int jt = 0; jt < 4; ++jt)
        acc[it][jt] = __builtin_amdgcn_mfma_f32_16x16x32_bf16(a[it], b[jt], acc[it][jt], 0, 0, 0);
    __builtin_amdgcn_s_setprio(0);
    __syncthreads();
  }

  #pragma unroll
  for (int it = 0; it < 2; ++it) {
    int mbase = m0 + wm * 32 + it * 16 + lh * 4;
    #pragma unroll
    for (int jt = 0; jt < 4; ++jt) {
      int nn = nn0 + wn * 64 + jt * 16 + l16;
      int bb = nn >> 10, p = nn & 1023;
      #pragma unroll
      for (int r = 0; r < 4; ++r) {
        size_t addr = ((size_t)bb * 512 + mbase + r) * 1024 + p;
        yout[addr] = acc[it][jt][r] + xres[addr];
      }
    }
  }
}

// ---------------- 6. flash attention: 8 waves / 128 q-rows, bh-fastest grid ----------------
__global__ __launch_bounds__(512) void attn_kernel(const unsigned short* __restrict__ qT,
                                                   const unsigned short* __restrict__ kT,
                                                   const unsigned short* __restrict__ vB,
                                                   const unsigned short* __restrict__ biasP,
                                                   unsigned short* __restrict__ attnout) {
  __shared__ unsigned short Kbuf[2][64 * 64];
  __shared__ unsigned short Vbuf[2][64 * 64];
  __shared__ unsigned short Ps[8][16 * 64];
  int tid = threadIdx.x;
  int bh = blockIdx.x;               // bh-fastest: XCD = bh%8
  int i0 = blockIdx.y * 128;
  int hh = bh & 7, bb = bh >> 3;
  int w = tid >> 6, lane = tid & 63, l16 = lane & 15, lh = lane >> 4;
  int rsub = lane >> 3, csub = lane & 7;
  int scsw = (csub ^ rsub) * 8;      // pre-swizzled source col (both-sides rule)

  const unsigned short* kbase = kT + (size_t)bh * NPOS * 64;
  const unsigned short* vbase = vB + (size_t)bh * 64 * NPOS;
  const unsigned short* bptr  = biasP + ((size_t)hh * 1024 + i0 + w * 16) * 1024 + l16 * 4;

  // Q fragments in registers (one q-row per lane)
  int qrow = i0 + w * 16 + l16;
  const unsigned short* qb = qT + ((size_t)bh * NPOS + qrow) * 64 + lh * 8;
  bf16x8 qreg[2];
  qreg[0] = *(const bf16x8*)&qb[0];
  qreg[1] = *(const bf16x8*)&qb[32];

  f32x4 o[5];                        // 0..3 output d-fragments, 4 = softmax denominator
  #pragma unroll
  for (int dt = 0; dt < 5; ++dt) o[dt] = (f32x4){0.f, 0.f, 0.f, 0.f};

  bf16x8 ones;
  {
    u16x8 tmp = {0x3F80, 0x3F80, 0x3F80, 0x3F80, 0x3F80, 0x3F80, 0x3F80, 0x3F80};
    ones = __builtin_bit_cast(bf16x8, tmp);
  }

  // stage tile jj: each of 8 waves stages 1 K-group + 1 V-group (1KB each)
  #define STAGE(Kd, Vd, jj) do {                                                        \
    gload16(&kbase[(size_t)((jj) + w * 8 + rsub) * 64 + scsw], &(Kd)[w * 512]);         \
    gload16(&vbase[(size_t)(w * 8 + rsub) * 1024 + (jj) + scsw], &(Vd)[w * 512]);       \
  } while (0)

  STAGE(Kbuf[0], Vbuf[0], 0);
  __syncthreads();                   // drains prologue staging

  #pragma unroll 1
  for (int t = 0; t < 16; ++t) {
    int j0 = t * 64;
    // issue next tile's staging first: in flight during this tile's compute
    if (t < 15) STAGE(Kbuf[(t + 1) & 1], Vbuf[(t + 1) & 1], j0 + 64);

    const unsigned short* Ks = Kbuf[t & 1];
    const unsigned short* Vs = Vbuf[t & 1];

    // bias preload (overlaps QK^T)
    u16x4 bv4[4];
    #pragma unroll
    for (int r = 0; r < 4; ++r) bv4[r] = *(const u16x4*)&bptr[(lh * 4 + r) * 1024 + j0];

    // ---- QK^T ----
    f32x4 s[4];
    #pragma unroll
    for (int jt = 0; jt < 4; ++jt) s[jt] = (f32x4){0.f, 0.f, 0.f, 0.f};
    __builtin_amdgcn_s_setprio(1);
    #pragma unroll
    for (int ks = 0; ks < 2; ++ks) {
      int koff = ks * 32 + lh * 8;
      #pragma unroll
      for (int jt = 0; jt < 4; ++jt) {
        bf16x8 bk = *(const bf16x8*)&Ks[sw(jt * 16 + l16, koff)];
        s[jt] = __builtin_amdgcn_mfma_f32_16x16x32_bf16(qreg[ks], bk, s[jt], 0, 0, 0);
      }
    }
    __builtin_amdgcn_s_setprio(0);

    // ---- elementwise softmax numerator: P = exp2(s + bias); no max, no cross-lane ----
    #pragma unroll
    for (int r = 0; r < 4; ++r) {
      int rloc = lh * 4 + r;
      #pragma unroll
      for (int jt = 0; jt < 4; ++jt) {
        float pv = __builtin_amdgcn_exp2f(s[jt][r] + bf2f(bv4[r][jt]));
        Ps[w][sw(rloc, jt * 16 + l16)] = f2bf(pv);
      }
    }

    // ---- PV (Ps wave-private: no barrier). o[4] accumulates the denominator ----
    __builtin_amdgcn_s_setprio(1);
    #pragma unroll
    for (int js = 0; js < 2; ++js) {
      int koff = js * 32 + lh * 8;
      bf16x8 pa = *(const bf16x8*)&Ps[w][sw(l16, koff)];
      #pragma unroll
      for (int dt = 0; dt < 4; ++dt) {
        bf16x8 vb = *(const bf16x8*)&Vs[sw(dt * 16 + l16, koff)];
        o[dt] = __builtin_amdgcn_mfma_f32_16x16x32_bf16(pa, vb, o[dt], 0, 0, 0);
      }
      o[4] = __builtin_amdgcn_mfma_f32_16x16x32_bf16(pa, ones, o[4], 0, 0, 0);
    }
    __builtin_amdgcn_s_setprio(0);

    // single barrier per tile: drains next tile's staging + protects buffer reuse
    __syncthreads();
  }

  #pragma unroll
  for (int r = 0; r < 4; ++r) {
    float inv = 1.f / o[4][r];
    int gi = i0 + w * 16 + lh * 4 + r;
    #pragma unroll
    for (int dt = 0; dt < 4; ++dt)
      attnout[((size_t)bb * 1024 + gi) * 512 + hh * 64 + dt * 16 + l16] = f2bf(o[dt][r] * inv);
  }
}

extern "C" void kernel_launch(void* const* d_in, const int* in_sizes, int n_in,
                              void* d_out, int out_size, void* d_ws, size_t ws_size,
                              hipStream_t stream) {
  const float* x     = (const float*)d_in[0];
  const float* gamma = (const float*)d_in[1];
  const float* w_qkv = (const float*)d_in[2];
  const float* w_out = (const float*)d_in[3];
  const float* cw0   = (const float*)d_in[4];
  const float* cb0   = (const float*)d_in[5];
  const float* cw1   = (const float*)d_in[6];
  const float* cb1   = (const float*)d_in[7];
  const float* cw2   = (const float*)d_in[8];
  const float* cb2   = (const float*)d_in[9];
  float* out = (float*)d_out;

  char* ws = (char*)d_ws;
  unsigned short* xnT   = (unsigned short*)(ws + 0);          // 8 MB
  unsigned short* wqb   = (unsigned short*)(ws + 8388608);    // 1.5 MB
  unsigned short* wob   = (unsigned short*)(ws + 9961472);    // 0.5 MB
  unsigned short* qT    = (unsigned short*)(ws + 10485760);   // 8 MB
  unsigned short* kT    = (unsigned short*)(ws + 18874368);   // 8 MB
  unsigned short* vB    = (unsigned short*)(ws + 27262976);   // 8 MB
  float*          table = (float*)(ws + 35651584);            // 128 KB
  unsigned short* biasP = (unsigned short*)(ws + 35782656);   // 16 MB
  unsigned short* aout  = (unsigned short*)(ws + 52559872);   // 8 MB

  cpb_kernel<<<256, 256, 0, stream>>>(cw0, cb0, cw1, cb1, cw2, cb2, table);
  setup_kernel<<<3328, 256, 0, stream>>>(w_qkv, w_out, wqb, wob, x, gamma, xnT);
  bias_expand<<<4096, 256, 0, stream>>>(table, biasP);
  gemm_qkv<<<dim3(64, 12), 256, 0, stream>>>(wqb, xnT, qT, kT, vB);
  attn_kernel<<<dim3(64, 8), 512, 0, stream>>>(qT, kT, vB, biasP, aout);
  gemm_out<<<dim3(64, 8), 256, 0, stream>>>(wob, aout, x, out);
}